// Round 22
// baseline (926.996 us; speedup 1.0000x reference)
//
#include <hip/hip_runtime.h>
#include <stdint.h>

#define K_DIM 4096
#define N_DIM 11008
#define M_DIM 8192

constexpr int BM = 128, BN = 128, BK = 64;
constexpr int NT  = K_DIM / BK;    // 64
constexpr int NZW = N_DIM / 8;     // 1376
constexpr int NXT = N_DIM / BN;    // 86
constexpr int MXT = M_DIM / BM;    // 64
constexpr int NWG = NXT * MXT;     // 5504 = 8 * 688
constexpr int TILE_ELEMS = BM * BK;  // 8192 f16 = 16 KiB per K-tile
constexpr size_t A16_BYTES = (size_t)M_DIM * K_DIM * 2;   // 64 MiB
constexpr size_t B16_BYTES = (size_t)N_DIM * K_DIM * 2;   // 86 MiB

typedef _Float16 f16x2 __attribute__((ext_vector_type(2)));
typedef _Float16 f16x8 __attribute__((ext_vector_type(8)));
typedef float    f32x4 __attribute__((ext_vector_type(4)));
union H8 { f16x8 v; f16x2 p[4]; };

// word w holds nibbles for k-offsets 0..7; output k-order (0,4,1,5,2,6,3,7).
// Exact: (1024+q) - (1024+z) is Sterbenz-exact; single rounding on *s.
__device__ __forceinline__ f16x8 dq_word(uint32_t w, f16x2 ss, f16x2 zz) {
    H8 r;
    uint32_t t0 = ( w        & 0x000F000Fu) | 0x64006400u;
    uint32_t t1 = ((w >> 4)  & 0x000F000Fu) | 0x64006400u;
    uint32_t t2 = ((w >> 8)  & 0x000F000Fu) | 0x64006400u;
    uint32_t t3 = ((w >> 12) & 0x000F000Fu) | 0x64006400u;
    r.p[0] = (__builtin_bit_cast(f16x2, t0) - zz) * ss;
    r.p[1] = (__builtin_bit_cast(f16x2, t1) - zz) * ss;
    r.p[2] = (__builtin_bit_cast(f16x2, t2) - zz) * ss;
    r.p[3] = (__builtin_bit_cast(f16x2, t3) - zz) * ss;
    return r.v;
}

// ========= pre-pass A: x fp32 -> f16, fragment-major 128-row tiles =========
// x16 layout: [mt(64)][kt(64)][fk(8)][row(128)][octet(8)], octet = pairs
// (e, e+4) of k = kt*64 + fk*8 + e  (matches dq_word's output permutation).
__global__ __launch_bounds__(256)
void prep_kernel(const float* __restrict__ x, _Float16* __restrict__ x16) {
    const int b  = blockIdx.x;          // mt*64 + kt
    const int mt = b >> 6, kt = b & 63;
    _Float16* dst = x16 + (size_t)b * TILE_ELEMS;
#pragma unroll
    for (int it = 0; it < 4; ++it) {
        const int o   = it * 256 + threadIdx.x;   // 0..1023 = fk*128 + row
        const int fk  = o >> 7, row = o & 127;
        const float* src = x + (size_t)(mt * 128 + row) * K_DIM + kt * 64 + fk * 8;
        f32x4 a0 = *(const f32x4*)src;
        f32x4 a1 = *(const f32x4*)(src + 4);
        H8 v;
#pragma unroll
        for (int j = 0; j < 4; ++j)
            v.p[j] = __builtin_bit_cast(f16x2, __builtin_amdgcn_cvt_pkrtz(a0[j], a1[j]));
        *(f16x8*)(dst + (size_t)o * 8) = v.v;
    }
}

// ========= pre-pass B: dequant qweight -> f16, fragment-major =========
// Bd layout: [ntile(86)][kt(64)][fk(8)][col(128)][octet(8)], octet = the
// dq_word k-permutation (matches A). One block per (kt, ntile); thread
// (fq = tid>>7, col = tid&127) handles fk = fq*4 + 0..3 at fixed col ->
// one s/z fetch per thread, coalesced qw reads and 16 B Bd writes.
__global__ __launch_bounds__(256)
void prepb_kernel(const uint32_t* __restrict__ qw, const uint32_t* __restrict__ qz,
                  const float* __restrict__ sc, _Float16* __restrict__ Bd) {
    const int b     = blockIdx.x;       // kt*86 + ntile
    const int kt    = b / NXT, ntile = b % NXT;
    const int col   = threadIdx.x & 127;
    const int fq    = threadIdx.x >> 7; // 0..1
    const int colg  = ntile * 128 + col;
    const int g     = kt >> 1;          // GROUP=128 = 2 K-tiles
    const float    s  = sc[(size_t)g * N_DIM + colg];
    const uint32_t zw = qz[(size_t)g * NZW + (colg >> 3)];
    const uint32_t zn = (zw >> (4 * (colg & 7))) & 15u;
    _Float16 sh = (_Float16)s;
    _Float16 zh = (_Float16)(float)(1024u + zn);
    f16x2 ss = {sh, sh}, zz = {zh, zh};
    _Float16* dst = Bd + (((size_t)(ntile * 64 + kt) * 8 + fq * 4) * 128 + col) * 8;
#pragma unroll
    for (int i = 0; i < 4; ++i) {
        const int fk = fq * 4 + i;
        const uint32_t w = qw[(size_t)(kt * 8 + fk) * N_DIM + colg];
        f16x8 v = dq_word(w, ss, zz);
        *(f16x8*)(dst + (size_t)i * 1024) = v;
    }
}

// Counted-vmcnt no-drain barrier (T4, R17-proven): wait until <=N VMEM
// outstanding; the N newest (B-frag loads) stay in flight across the barrier.
#define BARC(N) do {                                                         \
    __builtin_amdgcn_sched_barrier(0);                                       \
    asm volatile("s_waitcnt vmcnt(" #N ") lgkmcnt(0)" ::: "memory");         \
    __builtin_amdgcn_s_barrier();                                            \
    __builtin_amdgcn_sched_barrier(0);                                       \
} while (0)

// ===== 128x128 tile, 4 waves in N (wave-tile 128x32, acc=64), 16x16x32 MFMA.
// ===== A via global_load_lds DMA dbuf; B as PRE-DEQUANTIZED f16 fragments
// ===== loaded straight to registers (zero dq VALU in the main loop).
// (256,3): bfrag[2][4] (+24 regs vs R21) pushes past the (256,4) 128-cap.
__global__ __launch_bounds__(256, 3)
void qgemm_f16_kernel(const _Float16* __restrict__ x16, const _Float16* __restrict__ Bd,
                      const float* __restrict__ bias, float* __restrict__ out)
{
    __shared__ _Float16 As[2 * TILE_ELEMS];   // 2 x 16 KiB, fragment-major, linear

    const int tid  = threadIdx.x;
    const int lid  = (blockIdx.x & 7) * (NWG / 8) + (blockIdx.x >> 3); // XCD swizzle
    const int mt   = lid / NXT;
    const int nti  = lid % NXT;
    const int n0   = nti * BN;

    const int lane = tid & 63, wid = tid >> 6;   // wid 0..3 = N slot
    const int lr = lane & 15, lk = lane >> 4;

    f32x4 acc[8][2];
#pragma unroll
    for (int i = 0; i < 8; ++i)
#pragma unroll
        for (int j = 0; j < 2; ++j) {
            f32x4 z = {0.f, 0.f, 0.f, 0.f};
            acc[i][j] = z;
        }

    f16x8 bfrag[2][4];                // [set][ks*2+j] — B operand registers

    const _Float16* xsrc = x16 + (size_t)mt * (64 * TILE_ELEMS) + tid * 8;
    // B-frag address for (ks,j): bsrc + kt*8192 + (ks*4+lk)*1024 + (wid*32+j*16+lr)*8
    const _Float16* bsrc = Bd + (size_t)nti * (64 * 8192)
                              + (size_t)lk * 1024 + (wid * 32 + lr) * 8;

// 256 threads x 4 DMAs x 16 B = 16 KiB tile (linear dst, per intrinsic contract)
#define STAGE(BUF, KT) do {                                                  \
    const _Float16* s_ = xsrc + (size_t)(KT) * TILE_ELEMS;                   \
    _Float16* d_ = &As[(BUF) * TILE_ELEMS + tid * 8];                        \
    _Pragma("unroll") for (int it = 0; it < 4; ++it)                         \
        __builtin_amdgcn_global_load_lds(                                    \
            (const __attribute__((address_space(1))) void*)(s_ + it * 2048), \
            (__attribute__((address_space(3))) void*)(d_ + it * 2048), 16, 0, 0); \
    __builtin_amdgcn_sched_barrier(0);  /* pin: DMAs oldest in vmcnt queue */ \
    } while (0)

// 4 x 16 B loads: frag (ks,j) at offsets ks*4096 + j*128 elems from base
#define LOADB(SET, KT) do {                                                  \
    const _Float16* bp_ = bsrc + (size_t)(KT) * 8192;                        \
    bfrag[SET][0] = *(const f16x8*)(bp_);                                    \
    bfrag[SET][1] = *(const f16x8*)(bp_ + 128);                              \
    bfrag[SET][2] = *(const f16x8*)(bp_ + 4096);                             \
    bfrag[SET][3] = *(const f16x8*)(bp_ + 4096 + 128);                       \
    } while (0)

// wave spans ALL 128 rows (i=0..7), 32 cols (j=0..1). Fragment-major A reads:
// 16-lane beat = 256 B contiguous -> conflict-free (R15/R17: conflicts = 0).
#define COMPUTE(BUF, SET) do {                                               \
    _Pragma("unroll") for (int ks = 0; ks < 2; ++ks) {                       \
        const int fo_ = (BUF) * TILE_ELEMS + (ks * 4 + lk) * 1024 + lr * 8;  \
        __builtin_amdgcn_s_setprio(1);                                       \
        _Pragma("unroll") for (int i = 0; i < 8; ++i) {                      \
            f16x8 af_ = *(const f16x8*)&As[fo_ + i * 128];                   \
            acc[i][0] = __builtin_amdgcn_mfma_f32_16x16x32_f16(af_, bfrag[SET][ks * 2],     acc[i][0], 0, 0, 0); \
            acc[i][1] = __builtin_amdgcn_mfma_f32_16x16x32_f16(af_, bfrag[SET][ks * 2 + 1], acc[i][1], 0, 0, 0); \
        }                                                                    \
        __builtin_amdgcn_s_setprio(0);                                       \
    } } while (0)

    // -------- prologue: tile0 DMA oldest, B(0)->set0; wait DMAs only --------
    STAGE(0, 0);        // 4 DMAs (oldest)
    LOADB(0, 0);        // 4 B-frag loads (cross the barrier)
    BARC(4);            // tile-0 DMA landed; B(0) in flight (waited in COMPUTE)

    for (int kt2 = 0; kt2 < NT / 2; ++kt2) {
        const int t0 = 2 * kt2;
        // ---- even tile t0 (buf0, set0); DMA t0+1 -> buf1; B(t0+1) -> set1 ----
        STAGE(1, t0 + 1);       // DMAs oldest (macro pins with sched_barrier)
        LOADB(1, t0 + 1);       // stays in flight across barrier
        COMPUTE(0, 0);
        BARC(4);                // wait buf1 DMAs only; B loads cross

        // ---- odd tile t0+1 (buf1, set1); DMA t0+2 -> buf0; B(t0+2) -> set0 ----
        if (kt2 + 1 < NT / 2) {
            STAGE(0, t0 + 2);
            LOADB(0, t0 + 2);
            COMPUTE(1, 1);
            BARC(4);
        } else {
            COMPUTE(1, 1);      // final tile; epilogue doesn't touch LDS
        }
    }

#undef STAGE
#undef LOADB
#undef COMPUTE

    // epilogue: C/D layout col = lane&15, row = (lane>>4)*4 + reg
    const int ccol0 = n0 + wid * 32 + lr;
    float bj[2];
#pragma unroll
    for (int j = 0; j < 2; ++j) bj[j] = bias[ccol0 + j * 16];
    const int m0 = mt * BM;
#pragma unroll
    for (int i = 0; i < 8; ++i) {
        const int rbase = m0 + i * 16 + lk * 4;
#pragma unroll
        for (int j = 0; j < 2; ++j) {
            const int col = ccol0 + j * 16;
#pragma unroll
            for (int r = 0; r < 4; ++r)
                out[(size_t)(rbase + r) * N_DIM + col] = acc[i][j][r] + bj[j];
        }
    }
}

// ======= tier-2 fallback: R21 kernel (723 µs proven) — dq in-loop =======
__global__ __launch_bounds__(256, 4)
void qgemm_dma_kernel(const _Float16* __restrict__ x16, const uint32_t* __restrict__ qw,
                      const uint32_t* __restrict__ qz, const float* __restrict__ sc,
                      const float* __restrict__ bias, float* __restrict__ out)
{
    __shared__ _Float16 As[2 * TILE_ELEMS];

    const int tid  = threadIdx.x;
    const int lid  = (blockIdx.x & 7) * (NWG / 8) + (blockIdx.x >> 3);
    const int mt   = lid / NXT;
    const int n0   = (lid % NXT) * BN;

    const int lane = tid & 63, wid = tid >> 6;
    const int lr = lane & 15, lk = lane >> 4;

    f32x4 acc[8][2];
#pragma unroll
    for (int i = 0; i < 8; ++i)
#pragma unroll
        for (int j = 0; j < 2; ++j) { f32x4 z = {0.f,0.f,0.f,0.f}; acc[i][j] = z; }

    uint32_t breg[2][4];
    f16x2    ssv[2], zzv[2];
    float    s_nxt[2];
    uint32_t z_nxt[2];

    const int ncb = n0 + wid * 32 + lr;
    const int shz = 4 * (lr & 7);

    const _Float16* xsrc = x16 + (size_t)mt * (64 * TILE_ELEMS) + tid * 8;
    const uint32_t* qp0 = qw + (size_t)lk * N_DIM + ncb;
    const uint32_t* qp1 = qp0 + (size_t)4 * N_DIM;

#define STAGE(BUF, KT) do {                                                  \
    const _Float16* s_ = xsrc + (size_t)(KT) * TILE_ELEMS;                   \
    _Float16* d_ = &As[(BUF) * TILE_ELEMS + tid * 8];                        \
    _Pragma("unroll") for (int it = 0; it < 4; ++it)                         \
        __builtin_amdgcn_global_load_lds(                                    \
            (const __attribute__((address_space(1))) void*)(s_ + it * 2048), \
            (__attribute__((address_space(3))) void*)(d_ + it * 2048), 16, 0, 0); \
    __builtin_amdgcn_sched_barrier(0);                                       \
    } while (0)

#define LOADB(SET) do {                                                      \
    breg[SET][0] = qp0[0];  breg[SET][1] = qp0[16];                          \
    breg[SET][2] = qp1[0];  breg[SET][3] = qp1[16];                          \
    qp0 += (size_t)8 * N_DIM; qp1 += (size_t)8 * N_DIM; } while (0)

#define LOADSZ(G) do { _Pragma("unroll") for (int j = 0; j < 2; ++j) {       \
    s_nxt[j] = sc[(size_t)(G) * N_DIM + ncb + j * 16];                       \
    z_nxt[j] = qz[(size_t)(G) * NZW + (ncb >> 3) + j * 2]; } } while (0)

#define MAKESZ() do { _Pragma("unroll") for (int j = 0; j < 2; ++j) {        \
    _Float16 zh = (_Float16)(float)(1024u + ((z_nxt[j] >> shz) & 15u));      \
    _Float16 sh = (_Float16)s_nxt[j];                                        \
    f16x2 sp = {sh, sh}; ssv[j] = sp;                                        \
    f16x2 zp = {zh, zh}; zzv[j] = zp; } } while (0)

#define COMPUTE(BUF, SET) do {                                               \
    _Pragma("unroll") for (int ks = 0; ks < 2; ++ks) {                       \
        f16x8 bf0 = dq_word(breg[SET][ks * 2],     ssv[0], zzv[0]);          \
        f16x8 bf1 = dq_word(breg[SET][ks * 2 + 1], ssv[1], zzv[1]);          \
        const int fo_ = (BUF) * TILE_ELEMS + (ks * 4 + lk) * 1024 + lr * 8;  \
        __builtin_amdgcn_s_setprio(1);                                       \
        _Pragma("unroll") for (int i = 0; i < 8; ++i) {                      \
            f16x8 af_ = *(const f16x8*)&As[fo_ + i * 128];                   \
            acc[i][0] = __builtin_amdgcn_mfma_f32_16x16x32_f16(af_, bf0, acc[i][0], 0, 0, 0); \
            acc[i][1] = __builtin_amdgcn_mfma_f32_16x16x32_f16(af_, bf1, acc[i][1], 0, 0, 0); \
        }                                                                    \
        __builtin_amdgcn_s_setprio(0);                                       \
    } } while (0)

    LOADSZ(0);
    STAGE(0, 0);
    LOADB(0);
    BARC(4);

    for (int kt2 = 0; kt2 < NT / 2; ++kt2) {
        const int t0 = 2 * kt2;
        MAKESZ();
        STAGE(1, t0 + 1);
        LOADB(1);
        COMPUTE(0, 0);
        BARC(4);

        if (kt2 + 1 < NT / 2) {
            STAGE(0, t0 + 2);
            LOADB(0);
            LOADSZ(kt2 + 1);
            COMPUTE(1, 1);
            BARC(8);
        } else {
            COMPUTE(1, 1);
        }
    }

#undef STAGE
#undef LOADB
#undef LOADSZ
#undef MAKESZ
#undef COMPUTE

    const int ccol0 = n0 + wid * 32 + lr;
    float bj[2];
#pragma unroll
    for (int j = 0; j < 2; ++j) bj[j] = bias[ccol0 + j * 16];
    const int m0 = mt * BM;
#pragma unroll
    for (int i = 0; i < 8; ++i) {
        const int rbase = m0 + i * 16 + lk * 4;
#pragma unroll
        for (int j = 0; j < 2; ++j) {
            const int col = ccol0 + j * 16;
#pragma unroll
            for (int r = 0; r < 4; ++r)
                out[(size_t)(rbase + r) * N_DIM + col] = acc[i][j][r] + bj[j];
        }
    }
}

extern "C" void kernel_launch(void* const* d_in, const int* in_sizes, int n_in,
                              void* d_out, int out_size, void* d_ws, size_t ws_size,
                              hipStream_t stream) {
    const float*    xp = (const float*)d_in[0];
    const uint32_t* qw = (const uint32_t*)d_in[1];
    const uint32_t* qz = (const uint32_t*)d_in[2];
    const float*    sc = (const float*)d_in[3];
    const float*    bi = (const float*)d_in[4];
    float*          op = (float*)d_out;
    (void)in_sizes; (void)n_in; (void)out_size;

    _Float16* a16 = (_Float16*)d_ws;
    if (ws_size >= A16_BYTES + B16_BYTES) {
        _Float16* b16 = (_Float16*)((char*)d_ws + A16_BYTES);
        prep_kernel <<<dim3(MXT * NT), dim3(256), 0, stream>>>(xp, a16);
        prepb_kernel<<<dim3(NT * NXT), dim3(256), 0, stream>>>(qw, qz, sc, b16);
        qgemm_f16_kernel<<<dim3(NWG), dim3(256), 0, stream>>>(a16, b16, bi, op);
    } else {
        // tier-2 (ws >= 64 MiB, held in all prior rounds): R21 path
        prep_kernel<<<dim3(MXT * NT), dim3(256), 0, stream>>>(xp, a16);
        qgemm_dma_kernel<<<dim3(NWG), dim3(256), 0, stream>>>(a16, qw, qz, sc, bi, op);
    }
}

// Round 23
// 724.702 us; speedup vs baseline: 1.2791x; 1.2791x over previous
//
#include <hip/hip_runtime.h>
#include <stdint.h>

#define K_DIM 4096
#define N_DIM 11008
#define M_DIM 8192

constexpr int BM = 128, BN = 128, BK = 64;
constexpr int NT  = K_DIM / BK;    // 64
constexpr int NZW = N_DIM / 8;     // 1376
constexpr int NXT = N_DIM / BN;    // 86
constexpr int MXT = M_DIM / BM;    // 64
constexpr int NWG = NXT * MXT;     // 5504 = 8 * 688
constexpr int TILE_ELEMS = BM * BK;  // 8192 f16 = 16 KiB per K-tile

typedef _Float16 f16x2 __attribute__((ext_vector_type(2)));
typedef _Float16 f16x8 __attribute__((ext_vector_type(8)));
typedef float    f32x4 __attribute__((ext_vector_type(4)));
union H8 { f16x8 v; f16x2 p[4]; };

// word w holds nibbles for k-offsets 0..7; output k-order (0,4,1,5,2,6,3,7).
// Exact: (1024+q) - (1024+z) is Sterbenz-exact; single rounding on *s.
// NOTE (R22 lesson): keeping B 4-bit in HBM/L2 is a 4x bandwidth compression;
// pre-dequantizing B to f16 quadrupled FETCH (0.86 -> 3.0 GB) and regressed.
__device__ __forceinline__ f16x8 dq_word(uint32_t w, f16x2 ss, f16x2 zz) {
    H8 r;
    uint32_t t0 = ( w        & 0x000F000Fu) | 0x64006400u;
    uint32_t t1 = ((w >> 4)  & 0x000F000Fu) | 0x64006400u;
    uint32_t t2 = ((w >> 8)  & 0x000F000Fu) | 0x64006400u;
    uint32_t t3 = ((w >> 12) & 0x000F000Fu) | 0x64006400u;
    r.p[0] = (__builtin_bit_cast(f16x2, t0) - zz) * ss;
    r.p[1] = (__builtin_bit_cast(f16x2, t1) - zz) * ss;
    r.p[2] = (__builtin_bit_cast(f16x2, t2) - zz) * ss;
    r.p[3] = (__builtin_bit_cast(f16x2, t3) - zz) * ss;
    return r.v;
}

// ========= pre-pass: x fp32 -> f16, fragment-major 128-row tiles =========
// x16 layout: [mt(64)][kt(64)][fk(8)][row(128)][octet(8)], octet = pairs
// (e, e+4) of k = kt*64 + fk*8 + e  (matches dq_word's output permutation).
__global__ __launch_bounds__(256)
void prep_kernel(const float* __restrict__ x, _Float16* __restrict__ x16) {
    const int b  = blockIdx.x;          // mt*64 + kt
    const int mt = b >> 6, kt = b & 63;
    _Float16* dst = x16 + (size_t)b * TILE_ELEMS;
#pragma unroll
    for (int it = 0; it < 4; ++it) {
        const int o   = it * 256 + threadIdx.x;   // 0..1023 = fk*128 + row
        const int fk  = o >> 7, row = o & 127;
        const float* src = x + (size_t)(mt * 128 + row) * K_DIM + kt * 64 + fk * 8;
        f32x4 a0 = *(const f32x4*)src;
        f32x4 a1 = *(const f32x4*)(src + 4);
        H8 v;
#pragma unroll
        for (int j = 0; j < 4; ++j)
            v.p[j] = __builtin_bit_cast(f16x2, __builtin_amdgcn_cvt_pkrtz(a0[j], a1[j]));
        *(f16x8*)(dst + (size_t)o * 8) = v.v;
    }
}

// Counted-vmcnt no-drain barrier (T4): wait until <=N VMEM outstanding;
// the N newest (B/sz loads) stay in flight across the barrier.
#define BARC(N) do {                                                         \
    __builtin_amdgcn_sched_barrier(0);                                       \
    asm volatile("s_waitcnt vmcnt(" #N ") lgkmcnt(0)" ::: "memory");         \
    __builtin_amdgcn_s_barrier();                                            \
    __builtin_amdgcn_sched_barrier(0);                                       \
} while (0)

// ===== R21 kernel (723 µs proven): 128x128 tile, 4 waves in N (wave-tile
// ===== 128x32, acc=64), 16x16x32 MFMA, A via global_load_lds DMA dbuf,
// ===== counted-vmcnt barriers, T5 setprio around MFMA cluster.
__global__ __launch_bounds__(256, 4)
void qgemm_dma_kernel(const _Float16* __restrict__ x16, const uint32_t* __restrict__ qw,
                      const uint32_t* __restrict__ qz, const float* __restrict__ sc,
                      const float* __restrict__ bias, float* __restrict__ out)
{
    __shared__ _Float16 As[2 * TILE_ELEMS];   // 2 x 16 KiB, fragment-major, linear

    const int tid  = threadIdx.x;
    const int lid  = (blockIdx.x & 7) * (NWG / 8) + (blockIdx.x >> 3); // XCD swizzle
    const int mt   = lid / NXT;
    const int n0   = (lid % NXT) * BN;

    const int lane = tid & 63, wid = tid >> 6;   // wid 0..3 = N slot
    const int lr = lane & 15, lk = lane >> 4;

    f32x4 acc[8][2];
#pragma unroll
    for (int i = 0; i < 8; ++i)
#pragma unroll
        for (int j = 0; j < 2; ++j) {
            f32x4 z = {0.f, 0.f, 0.f, 0.f};
            acc[i][j] = z;
        }

    uint32_t breg[2][4];              // [set][ks*2+j]
    f16x2    ssv[2], zzv[2];
    float    s_nxt[2];
    uint32_t z_nxt[2];

    const int ncb = n0 + wid * 32 + lr;   // lane's base col; covers ncb, ncb+16
    const int shz = 4 * (lr & 7);

    const _Float16* xsrc = x16 + (size_t)mt * (64 * TILE_ELEMS) + tid * 8;
    const uint32_t* qp0 = qw + (size_t)lk * N_DIM + ncb;   // ks=0 word row
    const uint32_t* qp1 = qp0 + (size_t)4 * N_DIM;         // ks=1 word row

// 256 threads x 4 DMAs x 16 B = 16 KiB tile (linear dst, per intrinsic contract)
#define STAGE(BUF, KT) do {                                                  \
    const _Float16* s_ = xsrc + (size_t)(KT) * TILE_ELEMS;                   \
    _Float16* d_ = &As[(BUF) * TILE_ELEMS + tid * 8];                        \
    _Pragma("unroll") for (int it = 0; it < 4; ++it)                         \
        __builtin_amdgcn_global_load_lds(                                    \
            (const __attribute__((address_space(1))) void*)(s_ + it * 2048), \
            (__attribute__((address_space(3))) void*)(d_ + it * 2048), 16, 0, 0); \
    __builtin_amdgcn_sched_barrier(0);  /* pin: DMAs oldest in vmcnt queue */ \
    } while (0)

#define LOADB(SET) do {                                                      \
    breg[SET][0] = qp0[0];  breg[SET][1] = qp0[16];                          \
    breg[SET][2] = qp1[0];  breg[SET][3] = qp1[16];                          \
    qp0 += (size_t)8 * N_DIM; qp1 += (size_t)8 * N_DIM; } while (0)

#define LOADSZ(G) do { _Pragma("unroll") for (int j = 0; j < 2; ++j) {       \
    s_nxt[j] = sc[(size_t)(G) * N_DIM + ncb + j * 16];                       \
    z_nxt[j] = qz[(size_t)(G) * NZW + (ncb >> 3) + j * 2]; } } while (0)

#define MAKESZ() do { _Pragma("unroll") for (int j = 0; j < 2; ++j) {        \
    _Float16 zh = (_Float16)(float)(1024u + ((z_nxt[j] >> shz) & 15u));      \
    _Float16 sh = (_Float16)s_nxt[j];                                        \
    f16x2 sp = {sh, sh}; ssv[j] = sp;                                        \
    f16x2 zp = {zh, zh}; zzv[j] = zp; } } while (0)

// wave spans ALL 128 rows (i=0..7), 32 cols (j=0..1). Fragment-major reads:
// 16-lane beat = 256 B contiguous -> conflict-free (R15/R17/R21: conflicts=0).
#define COMPUTE(BUF, SET) do {                                               \
    _Pragma("unroll") for (int ks = 0; ks < 2; ++ks) {                       \
        f16x8 bf0 = dq_word(breg[SET][ks * 2],     ssv[0], zzv[0]);          \
        f16x8 bf1 = dq_word(breg[SET][ks * 2 + 1], ssv[1], zzv[1]);          \
        const int fo_ = (BUF) * TILE_ELEMS + (ks * 4 + lk) * 1024 + lr * 8;  \
        __builtin_amdgcn_s_setprio(1);                                       \
        _Pragma("unroll") for (int i = 0; i < 8; ++i) {                      \
            f16x8 af_ = *(const f16x8*)&As[fo_ + i * 128];                   \
            acc[i][0] = __builtin_amdgcn_mfma_f32_16x16x32_f16(af_, bf0, acc[i][0], 0, 0, 0); \
            acc[i][1] = __builtin_amdgcn_mfma_f32_16x16x32_f16(af_, bf1, acc[i][1], 0, 0, 0); \
        }                                                                    \
        __builtin_amdgcn_s_setprio(0);                                       \
    } } while (0)

    // -------- prologue: s/z(g0) oldest, tile0 DMA, B(0); wait DMAs only --------
    LOADSZ(0);          // 4 loads (oldest; retired by BARC(4))
    STAGE(0, 0);        // 4 DMAs
    LOADB(0);           // 4 loads (stay outstanding through barrier)
    BARC(4);            // tile-0 DMA landed; B(0) in flight

    for (int kt2 = 0; kt2 < NT / 2; ++kt2) {
        const int t0 = 2 * kt2;
        // ---- even tile t0 (buf0, set0); DMA t0+1 -> buf1 ----
        MAKESZ();               // group kt2: s/z loaded >=1 phase ago (landed)
        STAGE(1, t0 + 1);       // DMAs oldest (macro pins with sched_barrier)
        LOADB(1);               // B(t0+1): stays in flight across barrier
        COMPUTE(0, 0);
        BARC(4);                // wait buf1 DMAs only; B loads cross the barrier

        // ---- odd tile t0+1 (buf1, set1); DMA t0+2 -> buf0 ----
        if (kt2 + 1 < NT / 2) {
            STAGE(0, t0 + 2);
            LOADB(0);
            LOADSZ(kt2 + 1);    // next group's raw s/z (consumed 2 phases later)
            COMPUTE(1, 1);      // group kt2 (GROUP=128 = 2 K-tiles)
            BARC(8);            // wait buf0 DMAs; B + s/z loads cross barrier
        } else {
            COMPUTE(1, 1);      // final tile; epilogue doesn't touch LDS
        }
    }

#undef STAGE
#undef LOADB
#undef LOADSZ
#undef MAKESZ
#undef COMPUTE

    // epilogue: C/D layout col = lane&15, row = (lane>>4)*4 + reg
    const int ccol0 = n0 + wid * 32 + lr;
    float bj[2];
#pragma unroll
    for (int j = 0; j < 2; ++j) bj[j] = bias[ccol0 + j * 16];
    const int m0 = mt * BM;
#pragma unroll
    for (int i = 0; i < 8; ++i) {
        const int rbase = m0 + i * 16 + lk * 4;
#pragma unroll
        for (int j = 0; j < 2; ++j) {
            const int col = ccol0 + j * 16;
#pragma unroll
            for (int r = 0; r < 4; ++r)
                out[(size_t)(rbase + r) * N_DIM + col] = acc[i][j][r] + bj[j];
        }
    }
}

// ================= fallback (R14 kernel, 910 µs proven) for small ws =================
constexpr int FB_LDA = 64;

#define BAR() do {                                           \
    asm volatile("s_waitcnt lgkmcnt(0)" ::: "memory");       \
    __builtin_amdgcn_s_barrier();                            \
    __builtin_amdgcn_sched_barrier(0);                       \
} while (0)

__global__ __launch_bounds__(256, 3)
void qgemm_fb_kernel(const float* __restrict__ x, const uint32_t* __restrict__ qw,
                     const uint32_t* __restrict__ qz, const float* __restrict__ sc,
                     const float* __restrict__ bias, float* __restrict__ out)
{
    __shared__ _Float16 As[2][BM * FB_LDA];

    const int tid  = threadIdx.x;
    const int lid  = (blockIdx.x & 7) * (NWG / 8) + (blockIdx.x >> 3);
    const int m0   = (lid / NXT) * BM;
    const int n0   = (lid % NXT) * BN;

    const int lane = tid & 63, wid = tid >> 6;
    const int lr = lane & 15, lk = lane >> 4;
    const int sw = lr & 7;

    const int arow = tid >> 3;
    const int acp  = tid & 7;
    const int wslot = acp ^ (arow & 7);

    f32x4 acc[8][2];
#pragma unroll
    for (int i = 0; i < 8; ++i)
#pragma unroll
        for (int j = 0; j < 2; ++j) { f32x4 z = {0.f,0.f,0.f,0.f}; acc[i][j] = z; }

    f32x4    aS[4][2];
    uint32_t breg[2][4];
    f16x2    ssv[2], zzv[2];
    float    s_nxt[2];
    uint32_t z_nxt[2];

    const int ncb = n0 + wid * 32 + lr;
    const int shz = 4 * (lr & 7);
    const float* xbase = x + (size_t)(m0 + arow) * K_DIM + acp * 8;

    const uint32_t* qp0 = qw + (size_t)lk * N_DIM + ncb;
    const uint32_t* qp1 = qp0 + (size_t)4 * N_DIM;

#define A_LOAD(KT) do { const float* ap_ = xbase + (KT) * BK;                \
    _Pragma("unroll") for (int i = 0; i < 4; ++i) {                          \
        const float* src_ = ap_ + (size_t)(i * 32) * K_DIM;                  \
        aS[i][0] = *(const f32x4*)(src_);                                    \
        aS[i][1] = *(const f32x4*)(src_ + 4); } } while (0)

#define A_WRITE(BUF) do {                                                    \
    _Pragma("unroll") for (int i = 0; i < 4; ++i) { H8 v_;                   \
        _Pragma("unroll") for (int j = 0; j < 4; ++j)                        \
            v_.p[j] = __builtin_bit_cast(f16x2,                              \
                __builtin_amdgcn_cvt_pkrtz(aS[i][0][j], aS[i][1][j]));       \
        *(f16x8*)&As[BUF][(arow + i * 32) * FB_LDA + wslot * 8] = v_.v; } } while (0)

#define LOADB(SET) do {                                                      \
    breg[SET][0] = qp0[0];  breg[SET][1] = qp0[16];                          \
    breg[SET][2] = qp1[0];  breg[SET][3] = qp1[16];                          \
    qp0 += (size_t)8 * N_DIM; qp1 += (size_t)8 * N_DIM; } while (0)

#define LOADSZ(G) do { _Pragma("unroll") for (int j = 0; j < 2; ++j) {       \
    s_nxt[j] = sc[(size_t)(G) * N_DIM + ncb + j * 16];                       \
    z_nxt[j] = qz[(size_t)(G) * NZW + (ncb >> 3) + j * 2]; } } while (0)

#define MAKESZ() do { _Pragma("unroll") for (int j = 0; j < 2; ++j) {        \
    _Float16 zh = (_Float16)(float)(1024u + ((z_nxt[j] >> shz) & 15u));      \
    _Float16 sh = (_Float16)s_nxt[j];                                        \
    f16x2 sp = {sh, sh}; ssv[j] = sp;                                        \
    f16x2 zp = {zh, zh}; zzv[j] = zp; } } while (0)

#define COMPUTE(BUF, SET) do {                                               \
    _Pragma("unroll") for (int ks = 0; ks < 2; ++ks) {                       \
        f16x8 bf0 = dq_word(breg[SET][ks * 2],     ssv[0], zzv[0]);          \
        f16x8 bf1 = dq_word(breg[SET][ks * 2 + 1], ssv[1], zzv[1]);          \
        const int rs_ = ((ks * 4 + lk) ^ sw) * 8;                            \
        _Pragma("unroll") for (int i = 0; i < 8; ++i) {                      \
            f16x8 af_ = *(const f16x8*)&As[BUF][(i * 16 + lr) * FB_LDA + rs_]; \
            acc[i][0] = __builtin_amdgcn_mfma_f32_16x16x32_f16(af_, bf0, acc[i][0], 0, 0, 0); \
            acc[i][1] = __builtin_amdgcn_mfma_f32_16x16x32_f16(af_, bf1, acc[i][1], 0, 0, 0); \
        } } } while (0)

    LOADSZ(0);
    A_LOAD(0);
    LOADB(0);
    A_WRITE(0);
    BAR();

    for (int kt2 = 0; kt2 < NT / 2; ++kt2) {
        const int t0 = 2 * kt2;
        MAKESZ();
        A_LOAD(t0 + 1);
        LOADB(1);
        COMPUTE(0, 0);
        A_WRITE(1);
        BAR();

        if (kt2 + 1 < NT / 2) {
            A_LOAD(t0 + 2);
            LOADB(0);
            LOADSZ(kt2 + 1);
            COMPUTE(1, 1);
            A_WRITE(0);
        } else {
            COMPUTE(1, 1);
        }
        BAR();
    }

#undef A_LOAD
#undef A_WRITE
#undef LOADB
#undef LOADSZ
#undef MAKESZ
#undef COMPUTE

    const int ccol0 = n0 + wid * 32 + lr;
    float bj[2];
#pragma unroll
    for (int j = 0; j < 2; ++j) bj[j] = bias[ccol0 + j * 16];
#pragma unroll
    for (int i = 0; i < 8; ++i) {
        const int rbase = m0 + i * 16 + lk * 4;
#pragma unroll
        for (int j = 0; j < 2; ++j) {
            const int col = ccol0 + j * 16;
#pragma unroll
            for (int r = 0; r < 4; ++r)
                out[(size_t)(rbase + r) * N_DIM + col] = acc[i][j][r] + bj[j];
        }
    }
}

extern "C" void kernel_launch(void* const* d_in, const int* in_sizes, int n_in,
                              void* d_out, int out_size, void* d_ws, size_t ws_size,
                              hipStream_t stream) {
    const float*    xp = (const float*)d_in[0];
    const uint32_t* qw = (const uint32_t*)d_in[1];
    const uint32_t* qz = (const uint32_t*)d_in[2];
    const float*    sc = (const float*)d_in[3];
    const float*    bi = (const float*)d_in[4];
    float*          op = (float*)d_out;
    (void)in_sizes; (void)n_in; (void)out_size;

    const size_t need = (size_t)M_DIM * K_DIM * sizeof(_Float16); // 64 MiB
    if (ws_size >= need) {
        prep_kernel<<<dim3(MXT * NT), dim3(256), 0, stream>>>(xp, (_Float16*)d_ws);
        qgemm_dma_kernel<<<dim3(NWG), dim3(256), 0, stream>>>((const _Float16*)d_ws, qw, qz, sc, bi, op);
    } else {
        qgemm_fb_kernel<<<dim3(NWG), dim3(256), 0, stream>>>(xp, qw, qz, sc, bi, op);
    }
}